// Round 5
// baseline (630.832 us; speedup 1.0000x reference)
//
#include <hip/hip_runtime.h>
#include <math.h>

#define N 8192
#define IN_F 512
#define OUTF 64
#define TI 16
#define JSPLIT 8
#define JRANGE (N / JSPLIT)

typedef _Float16 f16x8 __attribute__((ext_vector_type(8)));
typedef float f32x4 __attribute__((ext_vector_type(4)));

// workspace layout (floats) — total 811024 floats = 3.24 MB
#define OFF_HT   0u          // hT: 64x8192 f16 = 262144 float-slots
#define OFF_S    262144u     // 8192
#define OFF_T    270336u     // 8192
#define OFF_TMAX 278528u     // 16
#define OFF_SP   278544u     // 8192
#define OFF_ACC  286736u     // 524288 (single copy — combined via atomics)

__device__ __forceinline__ unsigned enc_f32(float f) {
  unsigned b = __float_as_uint(f);
  return b ^ ((unsigned)((int)b >> 31) | 0x80000000u);
}

// ---------------------------------------------------------------------------
// K1: hT[f][j] = (f16)(input@W)[j][f], s = h@a1, t = h@a2.
// ---------------------------------------------------------------------------
__global__ __launch_bounds__(64) void k_precompute(
    const float* __restrict__ input, const float* __restrict__ W,
    const float* __restrict__ a, _Float16* __restrict__ hT,
    float* __restrict__ s, float* __restrict__ t) {
  const int lane = threadIdx.x;
  const int i0 = blockIdx.x * 4;

  float acc[4] = {0.f, 0.f, 0.f, 0.f};
  for (int c = 0; c < IN_F; c += 4) {
    const float w0 = W[(c + 0) * OUTF + lane];
    const float w1 = W[(c + 1) * OUTF + lane];
    const float w2 = W[(c + 2) * OUTF + lane];
    const float w3 = W[(c + 3) * OUTF + lane];
    #pragma unroll
    for (int r = 0; r < 4; r++) {
      const float4 iv = *(const float4*)(input + (size_t)(i0 + r) * IN_F + c);
      acc[r] += iv.x * w0 + iv.y * w1 + iv.z * w2 + iv.w * w3;
    }
  }

  union { _Float16 f[4]; uint2 u; } pk;
  #pragma unroll
  for (int r = 0; r < 4; r++) pk.f[r] = (_Float16)acc[r];
  *(uint2*)(hT + (size_t)lane * N + i0) = pk.u;

  const float a1v = a[lane];
  const float a2v = a[OUTF + lane];
  #pragma unroll
  for (int r = 0; r < 4; r++) {
    float sv = acc[r] * a1v;
    float tv = acc[r] * a2v;
    #pragma unroll
    for (int off = 1; off < 64; off <<= 1) {
      sv += __shfl_xor(sv, off);
      tv += __shfl_xor(tv, off);
    }
    if (lane == 0) {
      s[i0 + r] = sv;
      t[i0 + r] = tv;
    }
  }
}

// ---------------------------------------------------------------------------
// K1.5: tmax via atomicMax on monotone-encoded uint (memset-0 init).
// ---------------------------------------------------------------------------
__global__ __launch_bounds__(512) void k_tmax(const float* __restrict__ t,
                                              unsigned* __restrict__ tmax) {
  __shared__ float red[8];
  const int tid = threadIdx.x;
  float m = t[blockIdx.x * 512 + tid];
  #pragma unroll
  for (int off = 1; off < 64; off <<= 1) m = fmaxf(m, __shfl_xor(m, off));
  if ((tid & 63) == 0) red[tid >> 6] = m;
  __syncthreads();
  if (tid == 0) {
    #pragma unroll
    for (int w = 1; w < 8; w++) m = fmaxf(m, red[w]);
    atomicMax(tmax, enc_f32(m));
  }
}

// ---------------------------------------------------------------------------
// K2: MFMA attention partials, NO LDS. All operands loaded directly in
// MFMA fragment layout (16B/lane); compiler-managed waitcnts; latency
// hidden by occupancy (4096 waves = 16/CU). Atomic combine into accP/SP.
// Fragment roles identical to round-4 (end-to-end verified, absmax=f16 lvl).
// ---------------------------------------------------------------------------
__global__ __launch_bounds__(64) void k_attn(
    const _Float16* __restrict__ hT, const float* __restrict__ s,
    const float* __restrict__ t, const unsigned* __restrict__ tmaxp,
    const float* __restrict__ W_si, const float* __restrict__ W_ei,
    const float* __restrict__ adj_ad, const int* __restrict__ adj,
    float* __restrict__ SP, float* __restrict__ accP) {
  const int lane = threadIdx.x;
  const int q = lane >> 4;
  const int m = lane & 15;
  const int wid = blockIdx.x;
  const int split = wid & (JSPLIT - 1);
  const int i0 = (wid >> 3) * TI;
  const int jb = split * JRANGE;

  const float aei = fabsf(W_ei[0]);
  const float asi = fabsf(W_si[0]);
  const unsigned te = *tmaxp;
  const float tm = __uint_as_float((te & 0x80000000u) ? (te ^ 0x80000000u) : ~te);

  const float sr = s[i0 + m];
  const float xm = sr + tm;
  const float Mr = aei * fmaxf(xm, 0.2f * xm) + asi;  // row upper bound on e

  float S = 0.f;
  f32x4 acc[4];
  #pragma unroll
  for (int nb = 0; nb < 4; nb++) acc[nb] = (f32x4){0.f, 0.f, 0.f, 0.f};

  const size_t rowA = (size_t)(i0 + m) * N;  // adj/adj_ad row for this lane

  #pragma unroll 1
  for (int jt = 0; jt < JRANGE; jt += 64) {
    const int j0 = jb + jt;
    const int base = j0 + q * 8;  // this lane's k-run start (c=0)

    // ---- fragment-layout loads: e=0..7 for c=0 at base, c=1 at base+32 ----
    const float4 ad0 = *(const float4*)&adj_ad[rowA + base];
    const float4 ad1 = *(const float4*)&adj_ad[rowA + base + 4];
    const float4 ad2 = *(const float4*)&adj_ad[rowA + base + 32];
    const float4 ad3 = *(const float4*)&adj_ad[rowA + base + 36];
    const int4 mk0 = *(const int4*)&adj[rowA + base];
    const int4 mk1 = *(const int4*)&adj[rowA + base + 4];
    const int4 mk2 = *(const int4*)&adj[rowA + base + 32];
    const int4 mk3 = *(const int4*)&adj[rowA + base + 36];
    const float4 t0 = *(const float4*)&t[base];
    const float4 t1 = *(const float4*)&t[base + 4];
    const float4 t2 = *(const float4*)&t[base + 32];
    const float4 t3 = *(const float4*)&t[base + 36];

    const float ad[2][8] = {{ad0.x, ad0.y, ad0.z, ad0.w, ad1.x, ad1.y, ad1.z, ad1.w},
                            {ad2.x, ad2.y, ad2.z, ad2.w, ad3.x, ad3.y, ad3.z, ad3.w}};
    const int mk[2][8] = {{mk0.x, mk0.y, mk0.z, mk0.w, mk1.x, mk1.y, mk1.z, mk1.w},
                          {mk2.x, mk2.y, mk2.z, mk2.w, mk3.x, mk3.y, mk3.z, mk3.w}};
    const float tv[2][8] = {{t0.x, t0.y, t0.z, t0.w, t1.x, t1.y, t1.z, t1.w},
                            {t2.x, t2.y, t2.z, t2.w, t3.x, t3.y, t3.z, t3.w}};

    #pragma unroll
    for (int c = 0; c < 2; c++) {
      f16x8 fa;
      #pragma unroll
      for (int e = 0; e < 8; e++) {
        const float x = sr + tv[c][e];
        const float ee = aei * fmaxf(x, 0.2f * x) + asi * ad[c][e];
        const float p = (mk[c][e] > 0) ? __expf(ee - Mr) : 0.f;
        S += p;
        fa[e] = (_Float16)p;
      }
      #pragma unroll
      for (int nb = 0; nb < 4; nb++) {
        const f16x8 fb = *(const f16x8*)&hT[(size_t)(nb * 16 + m) * N + j0 +
                                            c * 32 + q * 8];
        acc[nb] = __builtin_amdgcn_mfma_f32_16x16x32_f16(fa, fb, acc[nb], 0, 0, 0);
      }
    }
  }

  // ---- epilogue: S over q-slices, atomic combine of j-splits ----
  S += __shfl_xor(S, 16);
  S += __shfl_xor(S, 32);
  if (lane < 16) atomicAdd(&SP[i0 + lane], S);

  // C/D layout (round-4 verified): out row = q*4+reg, out col = nb*16+m
  #pragma unroll
  for (int nb = 0; nb < 4; nb++) {
    #pragma unroll
    for (int reg = 0; reg < 4; reg++) {
      atomicAdd(&accP[(size_t)(i0 + q * 4 + reg) * OUTF + nb * 16 + m],
                acc[nb][reg]);
    }
  }
}

// ---------------------------------------------------------------------------
// K3: normalize + elu.
// ---------------------------------------------------------------------------
__global__ __launch_bounds__(256) void k_combine(const float* __restrict__ accP,
                                                 const float* __restrict__ SP,
                                                 float* __restrict__ out) {
  const int idx = blockIdx.x * 256 + threadIdx.x;
  const int i = idx >> 6;
  const float x = accP[idx] / SP[i];
  out[idx] = x > 0.f ? x : expm1f(x);
}

// ---------------------------------------------------------------------------
extern "C" void kernel_launch(void* const* d_in, const int* in_sizes, int n_in,
                              void* d_out, int out_size, void* d_ws, size_t ws_size,
                              hipStream_t stream) {
  const float* input  = (const float*)d_in[0];
  const float* W      = (const float*)d_in[1];
  const float* a      = (const float*)d_in[2];
  const float* W_si   = (const float*)d_in[3];
  const float* W_ei   = (const float*)d_in[4];
  const float* adj_ad = (const float*)d_in[5];
  const int*   adj    = (const int*)d_in[6];
  float* out = (float*)d_out;
  float* ws  = (float*)d_ws;

  _Float16* hT   = (_Float16*)(ws + OFF_HT);
  float* s       = ws + OFF_S;
  float* t       = ws + OFF_T;
  unsigned* tmax = (unsigned*)(ws + OFF_TMAX);
  float* SP      = ws + OFF_SP;
  float* accP    = ws + OFF_ACC;

  hipMemsetAsync(tmax, 0, 4, stream);
  hipMemsetAsync(SP, 0, N * sizeof(float), stream);
  hipMemsetAsync(accP, 0, (size_t)N * OUTF * sizeof(float), stream);
  k_precompute<<<N / 4, 64, 0, stream>>>(input, W, a, hT, s, t);
  k_tmax<<<N / 512, 512, 0, stream>>>(t, tmax);
  k_attn<<<(N / TI) * JSPLIT, 64, 0, stream>>>(hT, s, t, tmax, W_si, W_ei,
                                               adj_ad, adj, SP, accP);
  k_combine<<<(N * OUTF) / 256, 256, 0, stream>>>(accP, SP, out);
}

// Round 6
// 625.752 us; speedup vs baseline: 1.0081x; 1.0081x over previous
//
#include <hip/hip_runtime.h>
#include <math.h>

#define N 8192
#define IN_F 512
#define OUTF 64
#define TI 16
#define JSPLIT 8
#define JRANGE (N / JSPLIT)

typedef _Float16 f16x8 __attribute__((ext_vector_type(8)));
typedef float f32x4 __attribute__((ext_vector_type(4)));

typedef const void __attribute__((address_space(1)))* gptr_t;
typedef void __attribute__((address_space(3)))* lptr_t;

// workspace layout (floats) — total 811024 floats = 3.24 MB
#define OFF_HT   0u          // hT: 64x8192 f16 = 262144 float-slots
#define OFF_S    262144u     // 8192
#define OFF_T    270336u     // 8192
#define OFF_TMAX 278528u     // 16
#define OFF_SP   278544u     // 8192
#define OFF_ACC  286736u     // 524288 (single copy — combined via atomics)

__device__ __forceinline__ unsigned enc_f32(float f) {
  unsigned b = __float_as_uint(f);
  return b ^ ((unsigned)((int)b >> 31) | 0x80000000u);
}

// ---------------------------------------------------------------------------
// K1: hT[f][j] = (f16)(input@W)[j][f], s = h@a1, t = h@a2.
// ---------------------------------------------------------------------------
__global__ __launch_bounds__(64) void k_precompute(
    const float* __restrict__ input, const float* __restrict__ W,
    const float* __restrict__ a, _Float16* __restrict__ hT,
    float* __restrict__ s, float* __restrict__ t) {
  const int lane = threadIdx.x;
  const int i0 = blockIdx.x * 4;

  float acc[4] = {0.f, 0.f, 0.f, 0.f};
  for (int c = 0; c < IN_F; c += 4) {
    const float w0 = W[(c + 0) * OUTF + lane];
    const float w1 = W[(c + 1) * OUTF + lane];
    const float w2 = W[(c + 2) * OUTF + lane];
    const float w3 = W[(c + 3) * OUTF + lane];
    #pragma unroll
    for (int r = 0; r < 4; r++) {
      const float4 iv = *(const float4*)(input + (size_t)(i0 + r) * IN_F + c);
      acc[r] += iv.x * w0 + iv.y * w1 + iv.z * w2 + iv.w * w3;
    }
  }

  union { _Float16 f[4]; uint2 u; } pk;
  #pragma unroll
  for (int r = 0; r < 4; r++) pk.f[r] = (_Float16)acc[r];
  *(uint2*)(hT + (size_t)lane * N + i0) = pk.u;

  const float a1v = a[lane];
  const float a2v = a[OUTF + lane];
  #pragma unroll
  for (int r = 0; r < 4; r++) {
    float sv = acc[r] * a1v;
    float tv = acc[r] * a2v;
    #pragma unroll
    for (int off = 1; off < 64; off <<= 1) {
      sv += __shfl_xor(sv, off);
      tv += __shfl_xor(tv, off);
    }
    if (lane == 0) {
      s[i0 + r] = sv;
      t[i0 + r] = tv;
    }
  }
}

// ---------------------------------------------------------------------------
// K1.5: tmax via atomicMax on monotone-encoded uint (memset-0 init).
// ---------------------------------------------------------------------------
__global__ __launch_bounds__(512) void k_tmax(const float* __restrict__ t,
                                              unsigned* __restrict__ tmax) {
  __shared__ float red[8];
  const int tid = threadIdx.x;
  float m = t[blockIdx.x * 512 + tid];
  #pragma unroll
  for (int off = 1; off < 64; off <<= 1) m = fmaxf(m, __shfl_xor(m, off));
  if ((tid & 63) == 0) red[tid >> 6] = m;
  __syncthreads();
  if (tid == 0) {
    #pragma unroll
    for (int w = 1; w < 8; w++) m = fmaxf(m, red[w]);
    atomicMax(tmax, enc_f32(m));
  }
}

// ---------------------------------------------------------------------------
// K2: MFMA attention partials. Coalesced global_load_lds staging of adj/adj_ad
// into a fragment-layout LDS tile (element (m,kc) at float kc*64+m*4 —
// staging's lane*16 dest == 16 rows x one FULL 64B line per instr).
// Pipeline per tile: [hT/t loads for k] | STAGE(k+1) | vmcnt(8) | compute.
// In-order vmcnt retire: wait leaves only stage(k+1) outstanding.
// Single wave per block: no __syncthreads needed, manual vmcnt only.
// ---------------------------------------------------------------------------
__global__ __launch_bounds__(64, 3) void k_attn(
    const _Float16* __restrict__ hT, const float* __restrict__ s,
    const float* __restrict__ t, const unsigned* __restrict__ tmaxp,
    const float* __restrict__ W_si, const float* __restrict__ W_ei,
    const float* __restrict__ adj_ad, const int* __restrict__ adj,
    float* __restrict__ SP, float* __restrict__ accP) {
  __shared__ __align__(16) float bufA[2][1024];
  __shared__ __align__(16) int   bufM[2][1024];

  const int lane = threadIdx.x;
  const int q = lane >> 4;
  const int m = lane & 15;
  const int wid = blockIdx.x;
  const int split = wid & (JSPLIT - 1);
  const int i0 = (wid >> 3) * TI;
  const int jb = split * JRANGE;

  const float aei = fabsf(W_ei[0]);
  const float asi = fabsf(W_si[0]);
  const unsigned te = *tmaxp;
  const float tm = __uint_as_float((te & 0x80000000u) ? (te ^ 0x80000000u) : ~te);

  const float sr = s[i0 + m];
  const float xm = sr + tm;
  const float Mr = aei * fmaxf(xm, 0.2f * xm) + asi;  // row upper bound on e

  float S = 0.f;
  f32x4 acc[4];
  #pragma unroll
  for (int nb = 0; nb < 4; nb++) acc[nb] = (f32x4){0.f, 0.f, 0.f, 0.f};

  // staging source: lane L=(q,m) -> row i0+m, 16B chunk (g*4+q) of the tile.
  // per instr g: 16 rows x 64B contiguous (4 q-chunks) = 16 full lines.
  const size_t rowS = (size_t)(i0 + m) * N + (size_t)(q * 4);

  #define STAGE(b, j0s)                                                        \
    {                                                                          \
      _Pragma("unroll") for (int g = 0; g < 4; g++) {                          \
        __builtin_amdgcn_global_load_lds(                                      \
            (gptr_t)(adj_ad + rowS + (j0s) + g * 16),                          \
            (lptr_t)&bufA[b][g * 256], 16, 0, 0);                              \
      }                                                                        \
      _Pragma("unroll") for (int g = 0; g < 4; g++) {                          \
        __builtin_amdgcn_global_load_lds(                                      \
            (gptr_t)(adj + rowS + (j0s) + g * 16),                             \
            (lptr_t)&bufM[b][g * 256], 16, 0, 0);                              \
      }                                                                        \
    }

  STAGE(0, jb);
  int buf = 0;

  for (int jt = 0; jt < JRANGE; jt += 64) {
    const int j0 = jb + jt;

    // ---- (a) plain vector loads for THIS tile: hT fragments + t frags ----
    f16x8 fb[2][4];
    float4 tf[2][2];
    #pragma unroll
    for (int c = 0; c < 2; c++) {
      tf[c][0] = *(const float4*)&t[j0 + c * 32 + q * 8];
      tf[c][1] = *(const float4*)&t[j0 + c * 32 + q * 8 + 4];
      #pragma unroll
      for (int nb = 0; nb < 4; nb++)
        fb[c][nb] = *(const f16x8*)&hT[(size_t)(nb * 16 + m) * N + j0 +
                                       c * 32 + q * 8];
    }
    __builtin_amdgcn_sched_barrier(0);

    // ---- (b) stage NEXT tile into the other buffer ----
    if (jt + 64 < JRANGE) {
      STAGE(buf ^ 1, j0 + 64);
      __builtin_amdgcn_sched_barrier(0);
      // outstanding: stage(k)[8 oldest] + hT/t(k)[12] + stage(k+1)[8]
      __builtin_amdgcn_s_waitcnt(0xF78);  // vmcnt(8): stage(k)+hT/t done
    } else {
      __builtin_amdgcn_sched_barrier(0);
      __builtin_amdgcn_s_waitcnt(0xF70);  // vmcnt(0)
    }
    __builtin_amdgcn_sched_barrier(0);

    // ---- (c) compute from LDS fragments ----
    #pragma unroll
    for (int c = 0; c < 2; c++) {
      const int kc0 = c * 8 + q * 2;
      const float4 a0 = *(const float4*)&bufA[buf][kc0 * 64 + m * 4];
      const float4 a1 = *(const float4*)&bufA[buf][(kc0 + 1) * 64 + m * 4];
      const int4 k0 = *(const int4*)&bufM[buf][kc0 * 64 + m * 4];
      const int4 k1 = *(const int4*)&bufM[buf][(kc0 + 1) * 64 + m * 4];

      const float ad[8] = {a0.x, a0.y, a0.z, a0.w, a1.x, a1.y, a1.z, a1.w};
      const int mk[8] = {k0.x, k0.y, k0.z, k0.w, k1.x, k1.y, k1.z, k1.w};
      const float tv[8] = {tf[c][0].x, tf[c][0].y, tf[c][0].z, tf[c][0].w,
                           tf[c][1].x, tf[c][1].y, tf[c][1].z, tf[c][1].w};

      f16x8 fa;
      #pragma unroll
      for (int e = 0; e < 8; e++) {
        const float x = sr + tv[e];
        const float ee = aei * fmaxf(x, 0.2f * x) + asi * ad[e];
        const float p = (mk[e] > 0) ? __expf(ee - Mr) : 0.f;
        S += p;
        fa[e] = (_Float16)p;
      }
      #pragma unroll
      for (int nb = 0; nb < 4; nb++)
        acc[nb] = __builtin_amdgcn_mfma_f32_16x16x32_f16(fa, fb[c][nb],
                                                         acc[nb], 0, 0, 0);
    }
    buf ^= 1;
  }

  // ---- epilogue: S over q-slices, atomic combine of j-splits ----
  S += __shfl_xor(S, 16);
  S += __shfl_xor(S, 32);
  if (lane < 16) atomicAdd(&SP[i0 + lane], S);

  // C/D layout (round-4/5 verified): out row = q*4+reg, out col = nb*16+m
  #pragma unroll
  for (int nb = 0; nb < 4; nb++) {
    #pragma unroll
    for (int reg = 0; reg < 4; reg++) {
      atomicAdd(&accP[(size_t)(i0 + q * 4 + reg) * OUTF + nb * 16 + m],
                acc[nb][reg]);
    }
  }
}

// ---------------------------------------------------------------------------
// K3: normalize + elu.
// ---------------------------------------------------------------------------
__global__ __launch_bounds__(256) void k_combine(const float* __restrict__ accP,
                                                 const float* __restrict__ SP,
                                                 float* __restrict__ out) {
  const int idx = blockIdx.x * 256 + threadIdx.x;
  const int i = idx >> 6;
  const float x = accP[idx] / SP[i];
  out[idx] = x > 0.f ? x : expm1f(x);
}

// ---------------------------------------------------------------------------
extern "C" void kernel_launch(void* const* d_in, const int* in_sizes, int n_in,
                              void* d_out, int out_size, void* d_ws, size_t ws_size,
                              hipStream_t stream) {
  const float* input  = (const float*)d_in[0];
  const float* W      = (const float*)d_in[1];
  const float* a      = (const float*)d_in[2];
  const float* W_si   = (const float*)d_in[3];
  const float* W_ei   = (const float*)d_in[4];
  const float* adj_ad = (const float*)d_in[5];
  const int*   adj    = (const int*)d_in[6];
  float* out = (float*)d_out;
  float* ws  = (float*)d_ws;

  _Float16* hT   = (_Float16*)(ws + OFF_HT);
  float* s       = ws + OFF_S;
  float* t       = ws + OFF_T;
  unsigned* tmax = (unsigned*)(ws + OFF_TMAX);
  float* SP      = ws + OFF_SP;
  float* accP    = ws + OFF_ACC;

  hipMemsetAsync(tmax, 0, 4, stream);
  hipMemsetAsync(SP, 0, N * sizeof(float), stream);
  hipMemsetAsync(accP, 0, (size_t)N * OUTF * sizeof(float), stream);
  k_precompute<<<N / 4, 64, 0, stream>>>(input, W, a, hT, s, t);
  k_tmax<<<N / 512, 512, 0, stream>>>(t, tmax);
  k_attn<<<(N / TI) * JSPLIT, 64, 0, stream>>>(hT, s, t, tmax, W_si, W_ei,
                                               adj_ad, adj, SP, accP);
  k_combine<<<(N * OUTF) / 256, 256, 0, stream>>>(accP, SP, out);
}

// Round 7
// 583.843 us; speedup vs baseline: 1.0805x; 1.0718x over previous
//
#include <hip/hip_runtime.h>
#include <math.h>

#define N 8192
#define IN_F 512
#define OUTF 64
#define TI 16
#define JT 256               // j-cols per tile
#define NTILE (N / JT)       // 32 phases
#define RS 260               // padded LDS row stride (floats): banks spread

typedef _Float16 f16x8 __attribute__((ext_vector_type(8)));
typedef float f32x4 __attribute__((ext_vector_type(4)));

typedef const void __attribute__((address_space(1)))* gptr_t;
typedef void __attribute__((address_space(3)))* lptr_t;

// workspace layout (floats) — ~1.1 MB
#define OFF_HT   0u          // hT: 64x8192 f16 = 262144 float-slots
#define OFF_S    262144u     // 8192
#define OFF_T    270336u     // 8192
#define OFF_TMAX 278528u     // 16

__device__ __forceinline__ unsigned enc_f32(float f) {
  unsigned b = __float_as_uint(f);
  return b ^ ((unsigned)((int)b >> 31) | 0x80000000u);
}

// ---------------------------------------------------------------------------
// K1: hT[f][j] = (f16)(input@W)[j][f], s = h@a1, t = h@a2.
// ---------------------------------------------------------------------------
__global__ __launch_bounds__(64) void k_precompute(
    const float* __restrict__ input, const float* __restrict__ W,
    const float* __restrict__ a, _Float16* __restrict__ hT,
    float* __restrict__ s, float* __restrict__ t) {
  const int lane = threadIdx.x;
  const int i0 = blockIdx.x * 4;

  float acc[4] = {0.f, 0.f, 0.f, 0.f};
  for (int c = 0; c < IN_F; c += 4) {
    const float w0 = W[(c + 0) * OUTF + lane];
    const float w1 = W[(c + 1) * OUTF + lane];
    const float w2 = W[(c + 2) * OUTF + lane];
    const float w3 = W[(c + 3) * OUTF + lane];
    #pragma unroll
    for (int r = 0; r < 4; r++) {
      const float4 iv = *(const float4*)(input + (size_t)(i0 + r) * IN_F + c);
      acc[r] += iv.x * w0 + iv.y * w1 + iv.z * w2 + iv.w * w3;
    }
  }

  union { _Float16 f[4]; uint2 u; } pk;
  #pragma unroll
  for (int r = 0; r < 4; r++) pk.f[r] = (_Float16)acc[r];
  *(uint2*)(hT + (size_t)lane * N + i0) = pk.u;

  const float a1v = a[lane];
  const float a2v = a[OUTF + lane];
  #pragma unroll
  for (int r = 0; r < 4; r++) {
    float sv = acc[r] * a1v;
    float tv = acc[r] * a2v;
    #pragma unroll
    for (int off = 1; off < 64; off <<= 1) {
      sv += __shfl_xor(sv, off);
      tv += __shfl_xor(tv, off);
    }
    if (lane == 0) {
      s[i0 + r] = sv;
      t[i0 + r] = tv;
    }
  }
}

// ---------------------------------------------------------------------------
// K1.5: tmax via atomicMax on monotone-encoded uint (memset-0 init).
// ---------------------------------------------------------------------------
__global__ __launch_bounds__(512) void k_tmax(const float* __restrict__ t,
                                              unsigned* __restrict__ tmax) {
  __shared__ float red[8];
  const int tid = threadIdx.x;
  float m = t[blockIdx.x * 512 + tid];
  #pragma unroll
  for (int off = 1; off < 64; off <<= 1) m = fmaxf(m, __shfl_xor(m, off));
  if ((tid & 63) == 0) red[tid >> 6] = m;
  __syncthreads();
  if (tid == 0) {
    #pragma unroll
    for (int w = 1; w < 8; w++) m = fmaxf(m, red[w]);
    atomicMax(tmax, enc_f32(m));
  }
}

// ---------------------------------------------------------------------------
// K2: producer/consumer MFMA attention. 6 waves: 4 consumers + 2 producers.
// Producers stage 16x256 adj/adj_ad tiles via global_load_lds, ONE FULL ROW
// x 1KB CONTIGUOUS per instruction (rounds 4-6's 16-row x 64B scatter capped
// the memory system at ~2.7 TB/s). Double-buffered, plain __syncthreads.
// JSPLIT=1: 512 wg = 2/CU resident; epilogue reduces across consumer waves
// in LDS and writes normalized elu(out) directly.
// ---------------------------------------------------------------------------
__global__ __launch_bounds__(384, 3) void k_attn(
    const _Float16* __restrict__ hT, const float* __restrict__ s,
    const float* __restrict__ t, const unsigned* __restrict__ tmaxp,
    const float* __restrict__ W_si, const float* __restrict__ W_ei,
    const float* __restrict__ adj_ad, const int* __restrict__ adj,
    float* __restrict__ out) {
  __shared__ __align__(16) float bufA[2][TI * RS];  // 33280 B
  __shared__ __align__(16) int   bufM[2][TI * RS];  // 33280 B

  const int tid = threadIdx.x;
  const int wave = tid >> 6;
  const int lane = tid & 63;
  const int q = lane >> 4;
  const int m = lane & 15;
  const int i0 = blockIdx.x * TI;

  const float aei = fabsf(W_ei[0]);
  const float asi = fabsf(W_si[0]);
  const unsigned te = *tmaxp;
  const float tm = __uint_as_float((te & 0x80000000u) ? (te ^ 0x80000000u) : ~te);

  const float sr = s[i0 + m];
  const float xm = sr + tm;
  const float Mr = aei * fmaxf(xm, 0.2f * xm) + asi;  // row upper bound on e

  float S = 0.f;
  f32x4 acc[4];
  #pragma unroll
  for (int nb = 0; nb < 4; nb++) acc[nb] = (f32x4){0.f, 0.f, 0.f, 0.f};

  const int p = wave - 4;  // producer id (0,1) when wave>=4

  // One instr = one row x 1KB contiguous: lane reads 16B at row*N + j0 + lane*16B
  #define STAGE(b, j0s)                                                        \
    {                                                                          \
      _Pragma("unroll") for (int g = 0; g < 8; g++) {                          \
        const int row = p * 8 + g;                                             \
        __builtin_amdgcn_global_load_lds(                                      \
            (gptr_t)(adj_ad + (size_t)(i0 + row) * N + (j0s) + lane * 4),      \
            (lptr_t)&bufA[b][row * RS], 16, 0, 0);                             \
      }                                                                        \
      _Pragma("unroll") for (int g = 0; g < 8; g++) {                          \
        const int row = p * 8 + g;                                             \
        __builtin_amdgcn_global_load_lds(                                      \
            (gptr_t)(adj + (size_t)(i0 + row) * N + (j0s) + lane * 4),         \
            (lptr_t)&bufM[b][row * RS], 16, 0, 0);                             \
      }                                                                        \
    }

  if (wave >= 4) STAGE(0, 0);

  #pragma unroll 1
  for (int k = 0; k < NTILE; k++) {
    __syncthreads();  // B_k: producer drain => stage(k) resident in buf[k&1]

    if (wave >= 4) {
      if (k + 1 < NTILE) STAGE((k + 1) & 1, (k + 1) * JT);
    } else {
      const int buf = k & 1;
      const int j0 = k * JT;
      #pragma unroll
      for (int ck = 0; ck < 2; ck++) {
        const int kc = 2 * wave + ck;
        const int cb = j0 + kc * 32 + q * 8;
        const int lb = m * RS + kc * 32 + q * 8;

        const float4 tfa = *(const float4*)&t[cb];
        const float4 tfb = *(const float4*)&t[cb + 4];
        const float4 a0 = *(const float4*)&bufA[buf][lb];
        const float4 a1 = *(const float4*)&bufA[buf][lb + 4];
        const int4 k0 = *(const int4*)&bufM[buf][lb];
        const int4 k1 = *(const int4*)&bufM[buf][lb + 4];

        const float ad[8] = {a0.x, a0.y, a0.z, a0.w, a1.x, a1.y, a1.z, a1.w};
        const int mk[8] = {k0.x, k0.y, k0.z, k0.w, k1.x, k1.y, k1.z, k1.w};
        const float tv[8] = {tfa.x, tfa.y, tfa.z, tfa.w,
                             tfb.x, tfb.y, tfb.z, tfb.w};

        f16x8 fa;
        #pragma unroll
        for (int e = 0; e < 8; e++) {
          const float x = sr + tv[e];
          const float ee = aei * fmaxf(x, 0.2f * x) + asi * ad[e];
          const float pv = (mk[e] > 0) ? __expf(ee - Mr) : 0.f;
          S += pv;
          fa[e] = (_Float16)pv;
        }
        #pragma unroll
        for (int nb = 0; nb < 4; nb++) {
          const f16x8 fb = *(const f16x8*)&hT[(size_t)(nb * 16 + m) * N + cb];
          acc[nb] = __builtin_amdgcn_mfma_f32_16x16x32_f16(fa, fb, acc[nb],
                                                           0, 0, 0);
        }
      }
    }
  }

  // ---- epilogue: cross-wave reduce in LDS (reuse buffer 0; last tile used
  // buf 1 since NTILE-1=31 is odd — regions disjoint) ----
  float* aLDS = &bufA[0][0];                 // [4][16][64] = 4096 floats
  float* sLDS = (float*)&bufM[0][0];         // [4][64]

  if (wave < 4) {
    sLDS[wave * 64 + lane] = S;
    #pragma unroll
    for (int nb = 0; nb < 4; nb++) {
      #pragma unroll
      for (int reg = 0; reg < 4; reg++) {
        aLDS[wave * 1024 + (q * 4 + reg) * 64 + nb * 16 + m] = acc[nb][reg];
      }
    }
  }
  __syncthreads();

  if (wave < 4) {
    #pragma unroll
    for (int ii = 0; ii < 4; ii++) {
      const int e = tid + 256 * ii;
      const int r = e >> 6;
      const int f = e & 63;
      float num = 0.f, den = 0.f;
      #pragma unroll
      for (int w = 0; w < 4; w++) {
        num += aLDS[w * 1024 + r * 64 + f];
        #pragma unroll
        for (int qq = 0; qq < 4; qq++) den += sLDS[w * 64 + qq * 16 + r];
      }
      const float x = num / den;
      out[(size_t)(i0 + r) * OUTF + f] = x > 0.f ? x : expm1f(x);
    }
  }
}

// ---------------------------------------------------------------------------
extern "C" void kernel_launch(void* const* d_in, const int* in_sizes, int n_in,
                              void* d_out, int out_size, void* d_ws, size_t ws_size,
                              hipStream_t stream) {
  const float* input  = (const float*)d_in[0];
  const float* W      = (const float*)d_in[1];
  const float* a      = (const float*)d_in[2];
  const float* W_si   = (const float*)d_in[3];
  const float* W_ei   = (const float*)d_in[4];
  const float* adj_ad = (const float*)d_in[5];
  const int*   adj    = (const int*)d_in[6];
  float* out = (float*)d_out;
  float* ws  = (float*)d_ws;

  _Float16* hT   = (_Float16*)(ws + OFF_HT);
  float* s       = ws + OFF_S;
  float* t       = ws + OFF_T;
  unsigned* tmax = (unsigned*)(ws + OFF_TMAX);

  hipMemsetAsync(tmax, 0, 4, stream);
  k_precompute<<<N / 4, 64, 0, stream>>>(input, W, a, hT, s, t);
  k_tmax<<<N / 512, 512, 0, stream>>>(t, tmax);
  k_attn<<<N / TI, 384, 0, stream>>>(hT, s, t, tmax, W_si, W_ei,
                                     adj_ad, adj, out);
}